// Round 1
// baseline (238.553 us; speedup 1.0000x reference)
//
#include <hip/hip_runtime.h>
#include <math.h>

#define N_NODES 100000
#define N_EDGES 1000000
#define HDIM 128

// ---------------------------------------------------------------------------
// Kernel A: build the 16-entry per-head lookup tables.
// logit_h(e) = (fts[e]·wdiff_h + bdiff_h)/tau
//            = A_h[es_idx[rev[e]]] + B_h[ns_idx[src[e]]] + C_h   (tau folded in)
// where A_h[i] = edge_emb[i]·(W_top@wdiff_h)/tau,
//       B_h[j] = node_emb[j]·(W_bot@wdiff_h)/tau,
//       C_h    = (combine_b·wdiff_h + bdiff_h)/tau.
// Heads: 0=keep, 1=push, 2=push_node, 3=increment.
// tabs layout: [0..63] A (4x16), [64..127] B (4x16), [128..131] C.
// ---------------------------------------------------------------------------
__global__ void build_tables(
    const float* __restrict__ node_emb, const float* __restrict__ edge_emb,
    const float* __restrict__ combine_W, const float* __restrict__ combine_b,
    const float* __restrict__ keep_W,  const float* __restrict__ keep_b,
    const float* __restrict__ push_W,  const float* __restrict__ push_b,
    const float* __restrict__ pushn_W, const float* __restrict__ pushn_b,
    const float* __restrict__ inc_W,   const float* __restrict__ inc_b,
    const int* __restrict__ training_step,
    float* __restrict__ tabs)
{
    __shared__ float wdiff[4][HDIM];
    __shared__ float u[4][HDIM];   // W_top @ wdiff_h
    __shared__ float vv[4][HDIM];  // W_bot @ wdiff_h
    const int t = threadIdx.x;  // 256 threads

    int step = training_step[0];
    float tau;
    if (step == -1) {
        tau = 0.1f;  // TEMP_EVAL
    } else {
        float frac = fminf((float)step / 10000.0f, 1.0f);
        tau = 1.0f + (0.1f - 1.0f) * frac;
    }
    const float invtau = 1.0f / tau;

    for (int task = t; task < 4 * HDIM; task += 256) {
        const int h = task >> 7, d = task & 127;
        const float* W = (h == 0) ? keep_W : (h == 1) ? push_W : (h == 2) ? pushn_W : inc_W;
        wdiff[h][d] = W[d * 2 + 0] - W[d * 2 + 1];
    }
    __syncthreads();

    for (int task = t; task < 4 * HDIM; task += 256) {
        const int h = task >> 7, d = task & 127;
        float su = 0.f, sv = 0.f;
        for (int k = 0; k < HDIM; ++k) {
            su += combine_W[d * HDIM + k] * wdiff[h][k];
            sv += combine_W[(HDIM + d) * HDIM + k] * wdiff[h][k];
        }
        u[h][d] = su;
        vv[h][d] = sv;
    }
    __syncthreads();

    if (t < 64) {                       // A tables
        const int h = t >> 4, i = t & 15;
        float a = 0.f;
        for (int d = 0; d < HDIM; ++d) a += edge_emb[i * HDIM + d] * u[h][d];
        tabs[h * 16 + i] = a * invtau;
    } else if (t < 128) {               // B tables
        const int tt = t - 64, h = tt >> 4, i = tt & 15;
        float a = 0.f;
        for (int d = 0; d < HDIM; ++d) a += node_emb[i * HDIM + d] * vv[h][d];
        tabs[64 + h * 16 + i] = a * invtau;
    } else if (t < 132) {               // C constants
        const int h = t - 128;
        const float* b = (h == 0) ? keep_b : (h == 1) ? push_b : (h == 2) ? pushn_b : inc_b;
        float a = b[0] - b[1];
        for (int d = 0; d < HDIM; ++d) a += combine_b[d] * wdiff[h][d];
        tabs[128 + h] = a * invtau;
    }
}

// ---------------------------------------------------------------------------
// Kernel B: pack 4-bit state indices, zero accumulators.
// ---------------------------------------------------------------------------
__global__ void precompute(const int* __restrict__ node_states,
                           const int* __restrict__ edge_states,
                           unsigned char* __restrict__ es_idx,
                           unsigned char* __restrict__ ns_idx,
                           float* __restrict__ acc,
                           float* __restrict__ loss_out)
{
    const int e = blockIdx.x * blockDim.x + threadIdx.x;
    if (e < N_EDGES) {
        int4 st = ((const int4*)edge_states)[e];
        es_idx[e] = (unsigned char)(st.x + 2 * st.y + 4 * st.z + 8 * st.w);
    }
    if (e < N_NODES) {
        int4 st = ((const int4*)node_states)[e];
        ns_idx[e] = (unsigned char)(st.x + 2 * st.y + 4 * st.z + 8 * st.w);
        acc[e] = 0.f;
    }
    if (e == 0) *loss_out = 0.f;
}

// ---------------------------------------------------------------------------
// Kernel C: per-edge gates + scatter-add into acc[dst].
// ---------------------------------------------------------------------------
__global__ void edge_kernel(const float* __restrict__ s,
                            const int* __restrict__ src,
                            const int* __restrict__ dst,
                            const int* __restrict__ brev,
                            const unsigned char* __restrict__ es_idx,
                            const unsigned char* __restrict__ ns_idx,
                            const float* __restrict__ tabs,
                            float* __restrict__ acc,
                            float* __restrict__ out)
{
    __shared__ float st_[132];
    for (int i = threadIdx.x; i < 132; i += blockDim.x) st_[i] = tabs[i];
    __syncthreads();

    const int e = blockIdx.x * blockDim.x + threadIdx.x;
    if (e >= N_EDGES) return;

    const int rev = brev[e];
    const int si = src[e];
    const int di = dst[e];
    const float sv = s[e];
    const int ei = es_idx[rev];
    const int ni = ns_idx[si];

    const float lk  = st_[0 * 16 + ei] + st_[64 + 0 * 16 + ni] + st_[128 + 0];
    const float lp  = st_[1 * 16 + ei] + st_[64 + 1 * 16 + ni] + st_[128 + 1];
    const float lpn = st_[2 * 16 + ei] + st_[64 + 2 * 16 + ni] + st_[128 + 2];
    const float li  = st_[3 * 16 + ei] + st_[64 + 3 * 16 + ni] + st_[128 + 3];

    const float pk  = 1.f / (1.f + __expf(-lk));
    const float pp  = 1.f / (1.f + __expf(-lp));
    const float ppn = 1.f / (1.f + __expf(-lpn));
    const float pi  = 1.f / (1.f + __expf(-li));

    const float s_d = s[di];
    const float s_s = s[si];
    const float s_wo = sv - s_d;
    const float s_w  = s_wo + s_s;

    atomicAdd(&acc[di], pp * s_wo + ppn * s_w);
    out[e] = pi + sv * pk;   // increment + keep; edge_push added in finalize
}

// ---------------------------------------------------------------------------
// Kernel D: add edge_push, compute loss.
// ---------------------------------------------------------------------------
__global__ void finalize(const float* __restrict__ target,
                         const float* __restrict__ acc,
                         float* __restrict__ out,
                         float* __restrict__ loss_out)
{
    const int e = blockIdx.x * blockDim.x + threadIdx.x;
    float sq = 0.f;
    if (e < N_EDGES) {
        float v = out[e];
        if (e < N_NODES) v += acc[e];
        out[e] = v;
        const float d = target[e] - v;
        sq = d * d;
    }
    // wave(64) reduction then cross-wave via LDS
    #pragma unroll
    for (int off = 32; off > 0; off >>= 1) sq += __shfl_down(sq, off, 64);
    __shared__ float wsum[4];
    const int lane = threadIdx.x & 63, wid = threadIdx.x >> 6;
    if (lane == 0) wsum[wid] = sq;
    __syncthreads();
    if (threadIdx.x == 0) {
        const float tot = wsum[0] + wsum[1] + wsum[2] + wsum[3];
        atomicAdd(loss_out, tot * (1.0f / (float)N_EDGES));
    }
}

extern "C" void kernel_launch(void* const* d_in, const int* in_sizes, int n_in,
                              void* d_out, int out_size, void* d_ws, size_t ws_size,
                              hipStream_t stream) {
    const int*   node_states   = (const int*)d_in[0];
    const int*   edge_states   = (const int*)d_in[1];
    const float* scalars       = (const float*)d_in[2];
    const int*   edge_index    = (const int*)d_in[3];
    const int*   brev          = (const int*)d_in[4];
    const float* batch_scalars = (const float*)d_in[5];
    // d_in[6] = processor_step: batch_scalars axis-1 has size 1, index must be 0.
    const int*   training_step = (const int*)d_in[7];
    const float* node_emb  = (const float*)d_in[8];
    const float* edge_emb  = (const float*)d_in[9];
    const float* combine_W = (const float*)d_in[10];
    const float* combine_b = (const float*)d_in[11];
    const float* keep_W  = (const float*)d_in[12];
    const float* keep_b  = (const float*)d_in[13];
    const float* push_W  = (const float*)d_in[14];
    const float* push_b  = (const float*)d_in[15];
    const float* pushn_W = (const float*)d_in[16];
    const float* pushn_b = (const float*)d_in[17];
    const float* inc_W   = (const float*)d_in[18];
    const float* inc_b   = (const float*)d_in[19];

    float* out = (float*)d_out;  // [0..E) new_scalars, [E] loss

    // workspace layout
    char* ws = (char*)d_ws;
    float* tabs = (float*)ws;                                   // 132 floats (pad to 1 KiB)
    float* acc  = (float*)(ws + 1024);                          // N floats
    unsigned char* es_idx = (unsigned char*)(ws + 1024 + (size_t)N_NODES * 4);  // E bytes
    unsigned char* ns_idx = es_idx + N_EDGES;                   // N bytes

    const int* srcp = edge_index;
    const int* dstp = edge_index + N_EDGES;

    build_tables<<<1, 256, 0, stream>>>(node_emb, edge_emb, combine_W, combine_b,
                                        keep_W, keep_b, push_W, push_b,
                                        pushn_W, pushn_b, inc_W, inc_b,
                                        training_step, tabs);

    const int blocks = (N_EDGES + 255) / 256;
    precompute<<<blocks, 256, 0, stream>>>(node_states, edge_states, es_idx, ns_idx,
                                           acc, out + N_EDGES);
    edge_kernel<<<blocks, 256, 0, stream>>>(scalars, srcp, dstp, brev,
                                            es_idx, ns_idx, tabs, acc, out);
    finalize<<<blocks, 256, 0, stream>>>(batch_scalars, acc, out, out + N_EDGES);
}

// Round 3
// 186.300 us; speedup vs baseline: 1.2805x; 1.2805x over previous
//
#include <hip/hip_runtime.h>
#include <math.h>

#define N_NODES 100000
#define N_EDGES 1000000
#define HDIM 128

typedef float vfloat4 __attribute__((ext_vector_type(4)));

__device__ __forceinline__ float get_invtau(const int* __restrict__ training_step) {
    int step = training_step[0];
    float tau;
    if (step == -1) {
        tau = 0.1f;  // TEMP_EVAL
    } else {
        float frac = fminf((float)step / 10000.0f, 1.0f);
        tau = 1.0f + (0.1f - 1.0f) * frac;
    }
    return 1.0f / tau;
}

__device__ __forceinline__ float wave_reduce(float v) {
    #pragma unroll
    for (int off = 32; off > 0; off >>= 1) v += __shfl_down(v, off, 64);
    return v;
}

// ---------------------------------------------------------------------------
// Table stage 1: uv[0..511]    = u[h][d]  = (row d of W_top)·wdiff_h · invtau
//                uv[512..1023] = vv[h][d] = (row 128+d of combine_W)·wdiff_h · invtau
// One wave per output row; coalesced combine_W reads + shuffle reduce.
// Grid: 256 blocks x 256 threads (1024 waves = 1024 rows).
// ---------------------------------------------------------------------------
__global__ void tab_stage1(const float* __restrict__ cW,
                           const float* __restrict__ kW, const float* __restrict__ pW,
                           const float* __restrict__ pnW, const float* __restrict__ iW,
                           const int* __restrict__ tstep,
                           float* __restrict__ uv)
{
    __shared__ float wd[512];  // wdiff[h][d]
    const float invtau = get_invtau(tstep);
    for (int i = threadIdx.x; i < 512; i += 256) {
        const int h = i >> 7, d = i & 127;
        const float* W = (h == 0) ? kW : (h == 1) ? pW : (h == 2) ? pnW : iW;
        wd[i] = W[2 * d] - W[2 * d + 1];
    }
    __syncthreads();

    const int row  = blockIdx.x * 4 + (threadIdx.x >> 6);  // 0..1023
    const int lane = threadIdx.x & 63;
    const int half = row >> 9;          // 0 = u (W_top), 1 = vv (W_bot)
    const int r    = row & 511;
    const int h    = r >> 7, d = r & 127;
    const int cwrow = half * 128 + d;

    float p = cW[cwrow * 128 + lane]      * wd[h * 128 + lane]
            + cW[cwrow * 128 + 64 + lane] * wd[h * 128 + 64 + lane];
    p = wave_reduce(p);
    if (lane == 0) uv[row] = p * invtau;
}

// ---------------------------------------------------------------------------
// Table stage 2: tabs repacked as float4-per-index:
//   tabs[ei*4 + h]        (A, 64 floats)
//   tabs[64 + ni*4 + h]   (B, 64 floats)
//   tabs[128 + h]         (C, 4 floats)
// One wave per output; grid 33 blocks x 256 threads (132 waves).
// ---------------------------------------------------------------------------
__global__ void tab_stage2(const float* __restrict__ node_emb,
                           const float* __restrict__ edge_emb,
                           const float* __restrict__ cb,
                           const float* __restrict__ kW, const float* __restrict__ kb,
                           const float* __restrict__ pW, const float* __restrict__ pb,
                           const float* __restrict__ pnW, const float* __restrict__ pnb,
                           const float* __restrict__ iW, const float* __restrict__ ib,
                           const int* __restrict__ tstep,
                           const float* __restrict__ uv,
                           float* __restrict__ tabs)
{
    const int w = blockIdx.x * 4 + (threadIdx.x >> 6);  // 0..131
    if (w >= 132) return;
    const int lane = threadIdx.x & 63;
    const float invtau = get_invtau(tstep);

    float p;
    if (w < 128) {
        const int isB = w >> 6, h = (w >> 4) & 3, i = w & 15;
        const float* emb = isB ? node_emb : edge_emb;
        const float* uvp = uv + isB * 512 + h * 128;
        p = emb[i * 128 + lane] * uvp[lane] + emb[i * 128 + 64 + lane] * uvp[64 + lane];
    } else {
        const int h = w - 128;
        const float* W = (h == 0) ? kW : (h == 1) ? pW : (h == 2) ? pnW : iW;
        p = cb[lane]      * (W[2 * lane] - W[2 * lane + 1])
          + cb[64 + lane] * (W[2 * (64 + lane)] - W[2 * (64 + lane) + 1]);
    }
    p = wave_reduce(p);
    if (lane == 0) {
        if (w < 64) {
            const int h = (w >> 4) & 3, i = w & 15;
            tabs[i * 4 + h] = p;                       // invtau already folded via uv
        } else if (w < 128) {
            const int h = (w >> 4) & 3, i = w & 15;
            tabs[64 + i * 4 + h] = p;
        } else {
            const int h = w - 128;
            const float* b = (h == 0) ? kb : (h == 1) ? pb : (h == 2) ? pnb : ib;
            tabs[128 + h] = (p + b[0] - b[1]) * invtau;
        }
    }
}

// ---------------------------------------------------------------------------
// Pack 4-bit state indices, zero acc + loss.
// ---------------------------------------------------------------------------
__global__ void precompute(const int* __restrict__ node_states,
                           const int* __restrict__ edge_states,
                           unsigned char* __restrict__ es_idx,
                           unsigned char* __restrict__ ns_idx,
                           float* __restrict__ acc,
                           float* __restrict__ loss_out)
{
    const int e = blockIdx.x * blockDim.x + threadIdx.x;
    if (e < N_EDGES) {
        int4 st = ((const int4*)edge_states)[e];
        es_idx[e] = (unsigned char)(st.x + 2 * st.y + 4 * st.z + 8 * st.w);
    }
    if (e < N_NODES) {
        int4 st = ((const int4*)node_states)[e];
        ns_idx[e] = (unsigned char)(st.x + 2 * st.y + 4 * st.z + 8 * st.w);
        acc[e] = 0.f;
    }
    if (e == 0) *loss_out = 0.f;
}

// ---------------------------------------------------------------------------
// Per-edge gates + scatter-add + loss for e >= N. 4 edges/thread.
// ---------------------------------------------------------------------------
__global__ __launch_bounds__(256) void edge_kernel(
    const float* __restrict__ s,
    const int* __restrict__ src,
    const int* __restrict__ dst,
    const int* __restrict__ brev,
    const unsigned char* __restrict__ es_idx,
    const unsigned char* __restrict__ ns_idx,
    const float* __restrict__ tabs,
    const float* __restrict__ target,
    float* __restrict__ acc,
    float* __restrict__ out,
    float* __restrict__ loss_out)
{
    __shared__ float4 sf[33];  // [0..15] A4 by ei, [16..31] B4 by ni, [32] C4
    if (threadIdx.x < 33) sf[threadIdx.x] = ((const float4*)tabs)[threadIdx.x];
    __syncthreads();

    const int t = blockIdx.x * blockDim.x + threadIdx.x;
    const int e0 = t * 4;
    float lsum = 0.f;

    if (e0 < N_EDGES) {
        const int4   rv = ((const int4*)brev)[t];
        const int4   sr = ((const int4*)src)[t];
        const int4   ds = ((const int4*)dst)[t];
        const float4 sv = ((const float4*)s)[t];
        const vfloat4 tg = __builtin_nontemporal_load(&((const vfloat4*)target)[t]);

        const int rvv[4] = {rv.x, rv.y, rv.z, rv.w};
        const int srv[4] = {sr.x, sr.y, sr.z, sr.w};
        const int dsv[4] = {ds.x, ds.y, ds.z, ds.w};
        const float svv[4] = {sv.x, sv.y, sv.z, sv.w};
        const float tgv[4] = {tg.x, tg.y, tg.z, tg.w};

        // issue all gathers up front for latency overlap
        int ei[4], ni[4];
        float sd[4], ss[4];
        #pragma unroll
        for (int j = 0; j < 4; ++j) {
            ei[j] = es_idx[rvv[j]];
            ni[j] = ns_idx[srv[j]];
            sd[j] = s[dsv[j]];
            ss[j] = s[srv[j]];
        }

        const float4 c4 = sf[32];
        float ov[4];
        #pragma unroll
        for (int j = 0; j < 4; ++j) {
            const float4 a = sf[ei[j]];
            const float4 b = sf[16 + ni[j]];
            const float lk  = a.x + b.x + c4.x;
            const float lp  = a.y + b.y + c4.y;
            const float lpn = a.z + b.z + c4.z;
            const float li  = a.w + b.w + c4.w;
            const float pk  = 1.f / (1.f + __expf(-lk));
            const float pp  = 1.f / (1.f + __expf(-lp));
            const float ppn = 1.f / (1.f + __expf(-lpn));
            const float pi  = 1.f / (1.f + __expf(-li));

            const float s_wo = svv[j] - sd[j];
            const float s_w  = s_wo + ss[j];
            atomicAdd(&acc[dsv[j]], pp * s_wo + ppn * s_w);

            ov[j] = pi + svv[j] * pk;
            if (e0 + j >= N_NODES) {  // out is final for non-loop edges
                const float d = tgv[j] - ov[j];
                lsum += d * d;
            }
        }
        vfloat4 o4 = {ov[0], ov[1], ov[2], ov[3]};
        __builtin_nontemporal_store(o4, &((vfloat4*)out)[t]);
    }

    // block loss reduction
    lsum = wave_reduce(lsum);
    __shared__ float wsum[4];
    const int lane = threadIdx.x & 63, wid = threadIdx.x >> 6;
    if (lane == 0) wsum[wid] = lsum;
    __syncthreads();
    if (threadIdx.x == 0) {
        const float tot = wsum[0] + wsum[1] + wsum[2] + wsum[3];
        atomicAdd(loss_out, tot * (1.0f / (float)N_EDGES));
    }
}

// ---------------------------------------------------------------------------
// Add edge_push to the first N outputs, add their loss contribution.
// ---------------------------------------------------------------------------
__global__ void finalize_nodes(const float* __restrict__ target,
                               const float* __restrict__ acc,
                               float* __restrict__ out,
                               float* __restrict__ loss_out)
{
    const int e = blockIdx.x * blockDim.x + threadIdx.x;
    float sq = 0.f;
    if (e < N_NODES) {
        const float v = out[e] + acc[e];
        out[e] = v;
        const float d = target[e] - v;
        sq = d * d;
    }
    sq = wave_reduce(sq);
    __shared__ float wsum[4];
    const int lane = threadIdx.x & 63, wid = threadIdx.x >> 6;
    if (lane == 0) wsum[wid] = sq;
    __syncthreads();
    if (threadIdx.x == 0) {
        const float tot = wsum[0] + wsum[1] + wsum[2] + wsum[3];
        atomicAdd(loss_out, tot * (1.0f / (float)N_EDGES));
    }
}

extern "C" void kernel_launch(void* const* d_in, const int* in_sizes, int n_in,
                              void* d_out, int out_size, void* d_ws, size_t ws_size,
                              hipStream_t stream) {
    const int*   node_states   = (const int*)d_in[0];
    const int*   edge_states   = (const int*)d_in[1];
    const float* scalars       = (const float*)d_in[2];
    const int*   edge_index    = (const int*)d_in[3];
    const int*   brev          = (const int*)d_in[4];
    const float* batch_scalars = (const float*)d_in[5];
    // d_in[6] = processor_step: batch_scalars axis-1 has size 1 -> index 0.
    const int*   training_step = (const int*)d_in[7];
    const float* node_emb  = (const float*)d_in[8];
    const float* edge_emb  = (const float*)d_in[9];
    const float* combine_W = (const float*)d_in[10];
    const float* combine_b = (const float*)d_in[11];
    const float* keep_W  = (const float*)d_in[12];
    const float* keep_b  = (const float*)d_in[13];
    const float* push_W  = (const float*)d_in[14];
    const float* push_b  = (const float*)d_in[15];
    const float* pushn_W = (const float*)d_in[16];
    const float* pushn_b = (const float*)d_in[17];
    const float* inc_W   = (const float*)d_in[18];
    const float* inc_b   = (const float*)d_in[19];

    float* out = (float*)d_out;  // [0..E) new_scalars, [E] loss

    // workspace layout
    char* ws = (char*)d_ws;
    float* tabs = (float*)ws;                                    // 132 floats (pad 1 KiB)
    float* uv   = (float*)(ws + 1024);                           // 1024 floats (4 KiB)
    float* acc  = (float*)(ws + 1024 + 4096);                    // N floats
    unsigned char* es_idx = (unsigned char*)(ws + 1024 + 4096 + (size_t)N_NODES * 4);
    unsigned char* ns_idx = es_idx + N_EDGES;

    const int* srcp = edge_index;
    const int* dstp = edge_index + N_EDGES;

    tab_stage1<<<256, 256, 0, stream>>>(combine_W, keep_W, push_W, pushn_W, inc_W,
                                        training_step, uv);
    tab_stage2<<<33, 256, 0, stream>>>(node_emb, edge_emb, combine_b,
                                       keep_W, keep_b, push_W, push_b,
                                       pushn_W, pushn_b, inc_W, inc_b,
                                       training_step, uv, tabs);

    precompute<<<(N_EDGES + 255) / 256, 256, 0, stream>>>(node_states, edge_states,
                                                          es_idx, ns_idx, acc,
                                                          out + N_EDGES);

    const int ethreads = N_EDGES / 4;
    edge_kernel<<<(ethreads + 255) / 256, 256, 0, stream>>>(
        scalars, srcp, dstp, brev, es_idx, ns_idx, tabs, batch_scalars,
        acc, out, out + N_EDGES);

    finalize_nodes<<<(N_NODES + 255) / 256, 256, 0, stream>>>(
        batch_scalars, acc, out, out + N_EDGES);
}